// Round 5
// baseline (163.364 us; speedup 1.0000x reference)
//
#include <hip/hip_runtime.h>
#include <cmath>

#define BN 32
#define AN 32768
#define GN 64
#define APT 4                      // anchors per thread in k_fused
#define TPB 256                    // threads per block in k_fused
#define ANCH_PER_BLK (APT * TPB)   // 1024
#define SELCAP 8192                // survivor capacity per image (10x expected max)

// ---------------- new fast-path workspace layout (bytes) ----------------
// 0       : int    num_pos[32]
// 128     : float  loc_sum[32]
// 256     : float  posconf[32]
// 384     : float  negconf[32]
// 512     : uint2  selinfo[32]      (sel1, krem1)
// 768     : uint   scnt[32]
// 1024    : u64    gkey[B*G]        (16 KB)
// 17408   : uint   hist1[B][4096]   (512 KB)
// 541696  : u8     abyte[B*A]       (1 MB)
// 1590272 : f32    vals[B*A]        (4 MB)
// 5784576 : f32    surv[B][SELCAP]  (1 MB)
#define WS_NUMPOS(ws)  ((int*)(ws))
#define WS_LOC(ws)     ((float*)((char*)(ws) + 128))
#define WS_PCONF(ws)   ((float*)((char*)(ws) + 256))
#define WS_NCONF(ws)   ((float*)((char*)(ws) + 384))
#define WS_SELINFO(ws) ((uint2*)((char*)(ws) + 512))
#define WS_SCNT(ws)    ((unsigned*)((char*)(ws) + 768))
#define WS_GKEY(ws)    ((unsigned long long*)((char*)(ws) + 1024))
#define WS_HIST1(ws)   ((unsigned*)((char*)(ws) + 17408))
#define WS_ABYTE(ws)   ((unsigned char*)((char*)(ws) + 541696))
#define WS_VALS(ws)    ((float*)((char*)(ws) + 1590272))
#define WS_SURV(ws)    ((float*)((char*)(ws) + 5784576))
#define WS_NEW_NEED    (5784576 + (size_t)BN * SELCAP * 4)
#define WS_MEMSET_NEW  541696

// round-4 fallback layout
#define FB_GKEY(ws)    ((unsigned long long*)((char*)(ws) + 512))
#define FB_ABYTE(ws)   ((unsigned char*)((char*)(ws) + 16896))
#define WS_FB_NEED     (16896 + (size_t)BN * AN)

__device__ __forceinline__ float iou_exact(float4 a, float aarea,
                                           float4 g, float garea) {
    float ix0 = fmaxf(a.x, g.x), iy0 = fmaxf(a.y, g.y);
    float ix1 = fminf(a.z, g.z), iy1 = fminf(a.w, g.w);
    float iw = fmaxf(ix1 - ix0, 0.0f), ih = fmaxf(iy1 - iy0, 0.0f);
    float inter = iw * ih;
    return inter / (aarea + garea - inter + 1e-6f);
}

// ===================== fused IoU pass (both paths) =====================
// Computes every (anchor, gt) IoU exactly once.
// per-anchor best over g -> compressed byte; per-gt best over anchors via
// in-thread reduce + ONE u64 rotation shfl per j, then atomicMax on gkey.
// key = (iou_bits<<32) | ~anchor_idx  (max key == max iou, tie -> min idx).
__global__ __launch_bounds__(TPB) void k_fused(const float* __restrict__ anchors,
                                               const float* __restrict__ gt,
                                               unsigned long long* __restrict__ gkey,
                                               unsigned char* __restrict__ abyte) {
    __shared__ float4 sg[GN];
    __shared__ float  sga[GN];
    __shared__ unsigned long long skey[4][GN];

    int b = blockIdx.y;
    int tid = threadIdx.x;
    int lane = tid & 63, wave = tid >> 6;
    int blockbase = blockIdx.x * ANCH_PER_BLK;

    if (tid < GN) {
        float4 g = ((const float4*)gt)[b * GN + tid];
        sg[tid] = g;
        sga[tid] = (g.z - g.x) * (g.w - g.y);
    }
    __syncthreads();

    float4 ab[APT];
    float  sa[APT];
    unsigned naidx[APT];
    unsigned long long abest[APT];
    unsigned long long gacc = 0ull;      // best for gt == lane
#pragma unroll
    for (int k = 0; k < APT; ++k) {
        int a = blockbase + k * TPB + tid;
        ab[k] = ((const float4*)anchors)[a];
        sa[k] = (ab[k].z - ab[k].x) * (ab[k].w - ab[k].y) + 1e-6f;
        naidx[k] = ~(unsigned)a;
        abest[k] = 0ull;
    }

    for (int j = 0; j < GN; ++j) {
        int g = (lane + j) & 63;
        float4 gb = sg[g];
        float sgA = sga[g];
        unsigned long long glo = (unsigned long long)(unsigned)(63 - g);
        unsigned long long pbest = 0ull;
#pragma unroll
        for (int k = 0; k < APT; ++k) {
            float ix0 = fmaxf(ab[k].x, gb.x), iy0 = fmaxf(ab[k].y, gb.y);
            float ix1 = fminf(ab[k].z, gb.z), iy1 = fminf(ab[k].w, gb.w);
            float iw = fmaxf(ix1 - ix0, 0.0f), ih = fmaxf(iy1 - iy0, 0.0f);
            float inter = iw * ih;
            float denom = (sa[k] + sgA) - inter;
            float v = inter * __builtin_amdgcn_rcpf(denom);
            unsigned long long hib = ((unsigned long long)__float_as_uint(v)) << 32;
            unsigned long long kg = hib | glo;
            if (kg > abest[k]) abest[k] = kg;           // tie -> min g
            unsigned long long ka = hib | (unsigned long long)naidx[k];
            if (ka > pbest) pbest = ka;                 // tie -> min anchor idx
        }
        int src = (lane - j) & 63;
        unsigned long long pulled = __shfl(pbest, src, 64);
        if (pulled > gacc) gacc = pulled;
    }

#pragma unroll
    for (int k = 0; k < APT; ++k) {
        float biou = __uint_as_float((unsigned)(abest[k] >> 32));
        unsigned gsel = 63u - (unsigned)(abest[k] & 63ull);
        unsigned char byte = (unsigned char)(((biou > 0.5f) ? 0x80u : 0u) | gsel);
        abyte[(size_t)b * AN + blockbase + k * TPB + tid] = byte;
    }

    skey[wave][lane] = gacc;
    __syncthreads();
    if (tid < GN) {
        unsigned long long kk = skey[0][tid];
#pragma unroll
        for (int w = 1; w < 4; ++w) if (skey[w][tid] > kk) kk = skey[w][tid];
        atomicMax(&gkey[b * GN + tid], kk);
    }
}

// ===================== NEW tail pipeline =====================

// k_prep: grid (8, 32), 1024 thr. Each block owns 4096 anchors of one image.
// pos mask, num_pos/loc/posBCE partials, neg-loss vals -> ws, round-1 hist.
__global__ __launch_bounds__(1024) void k_prep(const float* __restrict__ bbox,
                                               const float* __restrict__ conf,
                                               const float* __restrict__ gt,
                                               const unsigned long long* __restrict__ gkey,
                                               const unsigned char* __restrict__ abyte,
                                               float* __restrict__ vals,
                                               unsigned* __restrict__ hist1,
                                               int* __restrict__ num_pos,
                                               float* __restrict__ loc_sum,
                                               float* __restrict__ posconf) {
    __shared__ unsigned hist[4096];      // 16 KB
    __shared__ unsigned bitmap[128];     // forced anchors within this 4096 range
    __shared__ float4 sgcs[GN];
    __shared__ float redL[16], redP[16];
    __shared__ int   redN[16];

    int blk = blockIdx.x, b = blockIdx.y, tid = threadIdx.x;
    int abase = blk * 4096;

    for (int i = tid; i < 4096; i += 1024) hist[i] = 0;
    if (tid < 128) bitmap[tid] = 0;
    if (tid < GN) {
        float4 g = ((const float4*)gt)[b * GN + tid];
        sgcs[tid] = make_float4((g.x + g.z) * 0.5f, (g.y + g.w) * 0.5f,
                                g.z - g.x, g.w - g.y);
    }
    __syncthreads();
    if (tid < GN) {
        unsigned long long kk = gkey[b * GN + tid];
        unsigned idx = ~(unsigned)(kk & 0xFFFFFFFFull);
        if ((int)(idx >> 12) == blk)
            atomicOr(&bitmap[(idx & 4095u) >> 5], 1u << (idx & 31u));
    }
    __syncthreads();

    int li = tid * 4;                       // 4 consecutive anchors
    size_t ia = (size_t)b * AN + abase + li;
    float4 c4 = ((const float4*)conf)[ia >> 2];
    uchar4 by4 = ((const uchar4*)abyte)[ia >> 2];
    float cc[4] = {c4.x, c4.y, c4.z, c4.w};
    unsigned bys[4] = {by4.x, by4.y, by4.z, by4.w};
    unsigned fbits = (bitmap[li >> 5] >> (li & 31)) & 0xFu;

    float v[4];
    float locv = 0.0f, pcv = 0.0f;
    int npv = 0;
#pragma unroll
    for (int e = 0; e < 4; ++e) {
        float p = cc[e];
        bool pos = (bys[e] & 0x80u) || ((fbits >> e) & 1u);
        if (pos) {
            float4 bb = ((const float4*)bbox)[ia + e];
            float4 m = sgcs[bys[e] & 63u];
            float d0 = (bb.x + bb.z) * 0.5f - m.x;
            float d1 = (bb.y + bb.w) * 0.5f - m.y;
            float d2 = (bb.z - bb.x) - m.z;
            float d3 = (bb.w - bb.y) - m.w;
            float ad = fabsf(d0); float s = (ad < 1.0f) ? 0.5f * d0 * d0 : ad - 0.5f;
            ad = fabsf(d1); s += (ad < 1.0f) ? 0.5f * d1 * d1 : ad - 0.5f;
            ad = fabsf(d2); s += (ad < 1.0f) ? 0.5f * d2 * d2 : ad - 0.5f;
            ad = fabsf(d3); s += (ad < 1.0f) ? 0.5f * d3 * d3 : ad - 0.5f;
            locv += s;
            pcv += -fmaxf(logf(p), -100.0f);
            v[e] = 0.0f;
            npv += 1;
        } else {
            v[e] = -fmaxf(log1pf(-p), -100.0f);   // neg_loss > 0
        }
        atomicAdd(&hist[__float_as_uint(v[e]) >> 20], 1u);
    }
    ((float4*)vals)[ia >> 2] = make_float4(v[0], v[1], v[2], v[3]);

    for (int off = 32; off; off >>= 1) {
        locv += __shfl_xor(locv, off);
        pcv  += __shfl_xor(pcv, off);
        npv  += __shfl_xor(npv, off);
    }
    int wave = tid >> 6, lane = tid & 63;
    if (lane == 0) { redL[wave] = locv; redP[wave] = pcv; redN[wave] = npv; }
    __syncthreads();
    if (tid == 0) {
        float L = 0.0f, P = 0.0f; int N = 0;
        for (int w = 0; w < 16; ++w) { L += redL[w]; P += redP[w]; N += redN[w]; }
        if (N) atomicAdd(&num_pos[b], N);
        atomicAdd(&loc_sum[b], L);
        atomicAdd(&posconf[b], P);
    }
    __syncthreads();
    for (int i = tid; i < 4096; i += 1024) {
        unsigned c = hist[i];
        if (c) atomicAdd(&hist1[b * 4096 + i], c);
    }
}

// k_selsum: grid (8, 32). Redundant round-1 selection per block (integer,
// deterministic); one scan: sum strictly-above-bin values, compact boundary
// bin survivors.
__global__ __launch_bounds__(1024) void k_selsum(const float* __restrict__ vals,
                                                 const unsigned* __restrict__ hist1,
                                                 const int* __restrict__ num_pos,
                                                 float* __restrict__ negconf,
                                                 float* __restrict__ surv,
                                                 unsigned* __restrict__ scnt,
                                                 uint2* __restrict__ selinfo) {
    __shared__ unsigned hist[4096];
    __shared__ float redL[16];
    __shared__ unsigned s_sel, s_krem;

    int blk = blockIdx.x, b = blockIdx.y, tid = threadIdx.x;

    for (int i = tid; i < 4096; i += 1024) hist[i] = hist1[b * 4096 + i];
    __syncthreads();

    int np = num_pos[b];
    unsigned k = (unsigned)min(3 * np, AN - np);
    if (k == 0) return;                         // negconf stays 0 (memset)

    unsigned krem = k;
    if (tid < 64) {
        int base = tid * 64;
        unsigned c = 0;
#pragma unroll
        for (int i = 0; i < 64; ++i) c += hist[base + i];
        unsigned S = c;
#pragma unroll
        for (int d = 1; d < 64; d <<= 1) {
            unsigned t = __shfl_down(S, d);
            if (tid + d < 64) S += t;
        }
        unsigned E = S - c;
        if (E < krem && krem <= S) {
            unsigned cum = E;
            for (int bin = base + 63; bin >= base; --bin) {
                unsigned h = hist[bin];
                cum += h;
                if (cum >= krem) { s_sel = (unsigned)bin; s_krem = krem - (cum - h); break; }
            }
        }
    }
    __syncthreads();
    unsigned sel1 = s_sel, krem1 = s_krem;
    if (blk == 0 && tid == 0) selinfo[b] = make_uint2(sel1, krem1);

    size_t base = (size_t)b * AN + blk * 4096;
    float4 v4 = ((const float4*)vals)[(base >> 2) + tid];
    float vv[4] = {v4.x, v4.y, v4.z, v4.w};
    float acc = 0.0f;
#pragma unroll
    for (int e = 0; e < 4; ++e) {
        unsigned bin = __float_as_uint(vv[e]) >> 20;
        if (bin > sel1) acc += vv[e];
        else if (bin == sel1) {
            unsigned p = atomicAdd(&scnt[b], 1u);
            if (p < SELCAP) surv[b * SELCAP + p] = vv[e];
        }
    }
    for (int off = 32; off; off >>= 1) acc += __shfl_xor(acc, off);
    int wave = tid >> 6, lane = tid & 63;
    if (lane == 0) redL[wave] = acc;
    __syncthreads();
    if (tid == 0) {
        float t = 0.0f;
        for (int w = 0; w < 16; ++w) t += redL[w];
        atomicAdd(&negconf[b], t);
    }
}

// k_sel2: 32 blocks, one per image. Resolve low 20 key bits among survivors
// (two tiny LDS radix rounds), add sum(v>T) + kremF*T.
__global__ __launch_bounds__(1024) void k_sel2(const float* __restrict__ surv,
                                               const unsigned* __restrict__ scnt,
                                               const uint2* __restrict__ selinfo,
                                               float* __restrict__ negconf) {
    __shared__ float sv[SELCAP];         // 32 KB
    __shared__ unsigned hist[4096];      // 16 KB
    __shared__ float redL[16];
    __shared__ unsigned s_sel, s_krem;

    int b = blockIdx.x, tid = threadIdx.x;
    uint2 si = selinfo[b];
    unsigned sel1 = si.x, krem1 = si.y;
    if (krem1 == 0) return;
    unsigned n = min(scnt[b], (unsigned)SELCAP);

    for (unsigned i = tid; i < n; i += 1024) sv[i] = surv[b * SELCAP + i];
    for (int i = tid; i < 4096; i += 1024) hist[i] = 0;
    __syncthreads();

    // round A: bins = (key>>8)&0xFFF (all survivors share top-12 bits == sel1)
    for (unsigned i = tid; i < n; i += 1024)
        atomicAdd(&hist[(__float_as_uint(sv[i]) >> 8) & 0xFFFu], 1u);
    __syncthreads();
    if (tid < 64) {
        int base = tid * 64;
        unsigned c = 0;
#pragma unroll
        for (int i = 0; i < 64; ++i) c += hist[base + i];
        unsigned S = c;
#pragma unroll
        for (int d = 1; d < 64; d <<= 1) {
            unsigned t = __shfl_down(S, d);
            if (tid + d < 64) S += t;
        }
        unsigned E = S - c;
        if (E < krem1 && krem1 <= S) {
            unsigned cum = E;
            for (int bin = base + 63; bin >= base; --bin) {
                unsigned h = hist[bin];
                cum += h;
                if (cum >= krem1) { s_sel = (unsigned)bin; s_krem = krem1 - (cum - h); break; }
            }
        }
    }
    __syncthreads();
    unsigned sel2 = s_sel, krem2 = s_krem;
    __syncthreads();
    if (tid < 256) hist[tid] = 0;
    __syncthreads();

    // round B: 256 bins on key&0xFF, masked to sel2
    for (unsigned i = tid; i < n; i += 1024) {
        unsigned key = __float_as_uint(sv[i]);
        if (((key >> 8) & 0xFFFu) == sel2) atomicAdd(&hist[key & 0xFFu], 1u);
    }
    __syncthreads();
    if (tid < 64) {
        int base = tid * 4;
        unsigned c = 0;
#pragma unroll
        for (int i = 0; i < 4; ++i) c += hist[base + i];
        unsigned S = c;
#pragma unroll
        for (int d = 1; d < 64; d <<= 1) {
            unsigned t = __shfl_down(S, d);
            if (tid + d < 64) S += t;
        }
        unsigned E = S - c;
        if (E < krem2 && krem2 <= S) {
            unsigned cum = E;
            for (int bin = base + 3; bin >= base; --bin) {
                unsigned h = hist[bin];
                cum += h;
                if (cum >= krem2) { s_sel = (unsigned)bin; s_krem = krem2 - (cum - h); break; }
            }
        }
    }
    __syncthreads();
    unsigned Tkey = (sel1 << 20) | (sel2 << 8) | s_sel;
    unsigned kremF = s_krem;
    float T = __uint_as_float(Tkey);

    float acc = 0.0f;
    for (unsigned i = tid; i < n; i += 1024) {
        if (__float_as_uint(sv[i]) > Tkey) acc += sv[i];
    }
    for (int off = 32; off; off >>= 1) acc += __shfl_xor(acc, off);
    int wave = tid >> 6, lane = tid & 63;
    if (lane == 0) redL[wave] = acc;
    __syncthreads();
    if (tid == 0) {
        float t = 0.0f;
        for (int w = 0; w < 16; ++w) t += redL[w];
        atomicAdd(&negconf[b], t + (float)kremF * T);
    }
}

// ===================== round-4 fallback tail (proven) =====================
__global__ __launch_bounds__(1024) void k_tail(const float* __restrict__ bbox,
                                               const float* __restrict__ conf,
                                               const float* __restrict__ gt,
                                               const unsigned long long* __restrict__ gkey,
                                               const unsigned char* __restrict__ abyte,
                                               int* __restrict__ num_pos,
                                               float* __restrict__ loc_sum,
                                               float* __restrict__ posconf,
                                               float* __restrict__ negconf) {
    __shared__ float vals[AN];
    __shared__ unsigned int hist[4096];
    __shared__ unsigned int bitmap[AN / 32];
    __shared__ float4 sgcs[GN];
    __shared__ float redL[16], redP[16];
    __shared__ int   redN[16];
    __shared__ int   s_np;
    __shared__ unsigned int s_sel, s_krem;

    int b = blockIdx.x;
    int tid = threadIdx.x;

    for (int i = tid; i < AN / 32; i += 1024) bitmap[i] = 0;
    if (tid < GN) {
        float4 g = ((const float4*)gt)[b * GN + tid];
        sgcs[tid] = make_float4((g.x + g.z) * 0.5f, (g.y + g.w) * 0.5f,
                                g.z - g.x, g.w - g.y);
    }
    __syncthreads();
    if (tid < GN) {
        unsigned long long kk = gkey[b * GN + tid];
        unsigned idx = ~(unsigned)(kk & 0xFFFFFFFFull);
        atomicOr(&bitmap[idx >> 5], 1u << (idx & 31));
    }
    __syncthreads();

    float locv = 0.0f, pcv = 0.0f;
    int npv = 0;
    for (int i = tid; i < AN; i += 1024) {
        size_t ia = (size_t)b * AN + i;
        unsigned byte = abyte[ia];
        float p = conf[ia];
        bool forced = (bitmap[i >> 5] >> (i & 31)) & 1u;
        bool pos = (byte & 0x80u) || forced;
        float v;
        if (pos) {
            float4 bb = ((const float4*)bbox)[ia];
            float4 m = sgcs[byte & 63u];
            float d0 = (bb.x + bb.z) * 0.5f - m.x;
            float d1 = (bb.y + bb.w) * 0.5f - m.y;
            float d2 = (bb.z - bb.x) - m.z;
            float d3 = (bb.w - bb.y) - m.w;
            float ad = fabsf(d0); float s = (ad < 1.0f) ? 0.5f * d0 * d0 : ad - 0.5f;
            ad = fabsf(d1); s += (ad < 1.0f) ? 0.5f * d1 * d1 : ad - 0.5f;
            ad = fabsf(d2); s += (ad < 1.0f) ? 0.5f * d2 * d2 : ad - 0.5f;
            ad = fabsf(d3); s += (ad < 1.0f) ? 0.5f * d3 * d3 : ad - 0.5f;
            locv += s;
            pcv += -fmaxf(logf(p), -100.0f);
            v = 0.0f;
            npv += 1;
        } else {
            v = -fmaxf(log1pf(-p), -100.0f);
        }
        vals[i] = v;
    }
    for (int off = 32; off; off >>= 1) {
        locv += __shfl_xor(locv, off);
        pcv  += __shfl_xor(pcv, off);
        npv  += __shfl_xor(npv, off);
    }
    int wave = tid >> 6, lane = tid & 63;
    if (lane == 0) { redL[wave] = locv; redP[wave] = pcv; redN[wave] = npv; }
    __syncthreads();
    if (tid == 0) {
        float L = 0.0f, P = 0.0f; int N = 0;
        for (int w = 0; w < 16; ++w) { L += redL[w]; P += redP[w]; N += redN[w]; }
        num_pos[b] = N; loc_sum[b] = L; posconf[b] = P; s_np = N;
    }
    __syncthreads();

    int np = s_np;
    unsigned int k = (unsigned int)min(3 * np, AN - np);
    if (k > 0) {
        unsigned int prefix = 0;
        unsigned int krem = k;
#pragma unroll
        for (int r = 0; r < 3; ++r) {
            const int shift = (r == 0) ? 20 : (r == 1) ? 8 : 0;
            const int width = (r == 2) ? 8 : 12;
            const unsigned int bmask = (1u << width) - 1u;
            const int hsh = shift + width;

            for (int i = tid; i < 4096; i += 1024) hist[i] = 0;
            __syncthreads();
            for (int i = tid; i < AN; i += 1024) {
                unsigned int key = __float_as_uint(vals[i]);
                bool m = (hsh >= 32) || ((key >> hsh) == (prefix >> hsh));
                if (m) atomicAdd(&hist[(key >> shift) & bmask], 1u);
            }
            __syncthreads();
            if (tid < 64) {
                int base = tid * 64;
                unsigned int c = 0;
#pragma unroll
                for (int i = 0; i < 64; ++i) c += hist[base + i];
                unsigned int S = c;
#pragma unroll
                for (int d = 1; d < 64; d <<= 1) {
                    unsigned int t = __shfl_down(S, d);
                    if (tid + d < 64) S += t;
                }
                unsigned int E = S - c;
                if (E < krem && krem <= S) {
                    unsigned int cum = E;
                    for (int bin = base + 63; bin >= base; --bin) {
                        unsigned int h = hist[bin];
                        cum += h;
                        if (cum >= krem) { s_sel = (unsigned)bin; s_krem = krem - (cum - h); break; }
                    }
                }
            }
            __syncthreads();
            prefix |= (s_sel << shift);
            krem = s_krem;
            __syncthreads();
        }
        float T = __uint_as_float(prefix);
        float part = 0.0f;
        for (int i = tid; i < AN; i += 1024) {
            float v = vals[i];
            if (v > T) part += v;
        }
        for (int off = 32; off; off >>= 1) part += __shfl_xor(part, off);
        if (lane == 0) redL[wave] = part;
        __syncthreads();
        if (tid == 0) {
            float t = 0.0f;
            for (int w = 0; w < 16; ++w) t += redL[w];
            negconf[b] = t + (float)krem * T;
        }
    } else {
        if (tid == 0) negconf[b] = 0.0f;
    }
}

// ===================== final reduction =====================
__global__ void k_final(const int* __restrict__ num_pos,
                        const float* __restrict__ loc_sum,
                        const float* __restrict__ posconf,
                        const float* __restrict__ negconf,
                        float* __restrict__ out) {
    int tid = threadIdx.x;
    int np = 0; float lc = 0.0f, pc = 0.0f, nc = 0.0f;
    if (tid < BN) { np = num_pos[tid]; lc = loc_sum[tid]; pc = posconf[tid]; nc = negconf[tid]; }
    for (int off = 32; off; off >>= 1) {
        np += __shfl_xor(np, off); lc += __shfl_xor(lc, off);
        pc += __shfl_xor(pc, off); nc += __shfl_xor(nc, off);
    }
    if (tid == 0) {
        float tp = (float)max(1, np);
        float loc_loss = lc / tp;
        float conf_loss = (pc + nc) / tp;
        out[0] = loc_loss + conf_loss;
        out[1] = conf_loss;
        out[2] = loc_loss;
    }
}

extern "C" void kernel_launch(void* const* d_in, const int* in_sizes, int n_in,
                              void* d_out, int out_size, void* d_ws, size_t ws_size,
                              hipStream_t stream) {
    const float* bbox    = (const float*)d_in[0];   // [B,A,4]
    const float* conf    = (const float*)d_in[1];   // [B,A]
    const float* anchors = (const float*)d_in[2];   // [A,4]
    const float* gt      = (const float*)d_in[3];   // [B,G,4]
    float* out = (float*)d_out;

    if (ws_size >= WS_NEW_NEED) {
        // zero scalars + selinfo + scnt + gkey + hist1
        hipMemsetAsync(d_ws, 0, WS_MEMSET_NEW, stream);

        dim3 g1(AN / ANCH_PER_BLK, BN);   // (32, 32)
        k_fused<<<g1, TPB, 0, stream>>>(anchors, gt, WS_GKEY(d_ws), WS_ABYTE(d_ws));

        dim3 g2(8, BN);
        k_prep<<<g2, 1024, 0, stream>>>(bbox, conf, gt, WS_GKEY(d_ws), WS_ABYTE(d_ws),
                                        WS_VALS(d_ws), WS_HIST1(d_ws),
                                        WS_NUMPOS(d_ws), WS_LOC(d_ws), WS_PCONF(d_ws));

        k_selsum<<<g2, 1024, 0, stream>>>(WS_VALS(d_ws), WS_HIST1(d_ws), WS_NUMPOS(d_ws),
                                          WS_NCONF(d_ws), WS_SURV(d_ws), WS_SCNT(d_ws),
                                          WS_SELINFO(d_ws));

        k_sel2<<<BN, 1024, 0, stream>>>(WS_SURV(d_ws), WS_SCNT(d_ws), WS_SELINFO(d_ws),
                                        WS_NCONF(d_ws));

        k_final<<<1, 64, 0, stream>>>(WS_NUMPOS(d_ws), WS_LOC(d_ws), WS_PCONF(d_ws),
                                      WS_NCONF(d_ws), out);
    } else {
        // round-4 proven path
        hipMemsetAsync((char*)d_ws + 512, 0, 16384, stream);
        dim3 g1(AN / ANCH_PER_BLK, BN);
        k_fused<<<g1, TPB, 0, stream>>>(anchors, gt, FB_GKEY(d_ws), FB_ABYTE(d_ws));
        k_tail<<<BN, 1024, 0, stream>>>(bbox, conf, gt, FB_GKEY(d_ws), FB_ABYTE(d_ws),
                                        WS_NUMPOS(d_ws), WS_LOC(d_ws), WS_PCONF(d_ws),
                                        WS_NCONF(d_ws));
        k_final<<<1, 64, 0, stream>>>(WS_NUMPOS(d_ws), WS_LOC(d_ws), WS_PCONF(d_ws),
                                      WS_NCONF(d_ws), out);
    }
}

// Round 6
// 100.315 us; speedup vs baseline: 1.6285x; 1.6285x over previous
//
#include <hip/hip_runtime.h>
#include <cmath>

#define BN 32
#define AN 32768
#define GN 64
#define APT 4                      // anchors per thread in k_fused
#define TPB 256                    // threads per block in k_fused
#define ANCH_PER_BLK (APT * TPB)   // 1024
#define CAP 8192                   // LDS survivor capacity (>4x worst-case ~1500)

// ---------------- workspace layout (bytes) ----------------
// 0      : int    num_pos[32]
// 128    : float  loc_sum[32]
// 256    : float  posconf[32]
// 384    : float  negconf[32]
// 1024   : u64    gkey[B*G]        (16 KB)
// 17408  : uint   hist1[B][4096]   (512 KB)
// 541696 : u8     abyte[B*A]       (1 MB)   -- not memset (fully overwritten)
#define WS_NUMPOS(ws)  ((int*)(ws))
#define WS_LOC(ws)     ((float*)((char*)(ws) + 128))
#define WS_PCONF(ws)   ((float*)((char*)(ws) + 256))
#define WS_NCONF(ws)   ((float*)((char*)(ws) + 384))
#define WS_GKEY(ws)    ((unsigned long long*)((char*)(ws) + 1024))
#define WS_HIST1(ws)   ((unsigned*)((char*)(ws) + 17408))
#define WS_ABYTE(ws)   ((unsigned char*)((char*)(ws) + 541696))
#define WS_MEMSET      541696

// ===================== fused IoU pass =====================
// Computes every (anchor, gt) IoU exactly once.
// per-anchor best over g -> compressed byte; per-gt best over anchors via
// in-thread reduce + ONE u64 rotation shfl per j, then atomicMax on gkey.
// key = (iou_bits<<32) | ~anchor_idx  (max key == max iou, tie -> min idx).
__global__ __launch_bounds__(TPB) void k_fused(const float* __restrict__ anchors,
                                               const float* __restrict__ gt,
                                               unsigned long long* __restrict__ gkey,
                                               unsigned char* __restrict__ abyte) {
    __shared__ float4 sg[GN];
    __shared__ float  sga[GN];
    __shared__ unsigned long long skey[4][GN];

    int b = blockIdx.y;
    int tid = threadIdx.x;
    int lane = tid & 63, wave = tid >> 6;
    int blockbase = blockIdx.x * ANCH_PER_BLK;

    if (tid < GN) {
        float4 g = ((const float4*)gt)[b * GN + tid];
        sg[tid] = g;
        sga[tid] = (g.z - g.x) * (g.w - g.y);
    }
    __syncthreads();

    float4 ab[APT];
    float  sa[APT];
    unsigned naidx[APT];
    unsigned long long abest[APT];
    unsigned long long gacc = 0ull;      // best for gt == lane
#pragma unroll
    for (int k = 0; k < APT; ++k) {
        int a = blockbase + k * TPB + tid;
        ab[k] = ((const float4*)anchors)[a];
        sa[k] = (ab[k].z - ab[k].x) * (ab[k].w - ab[k].y) + 1e-6f;
        naidx[k] = ~(unsigned)a;
        abest[k] = 0ull;
    }

    for (int j = 0; j < GN; ++j) {
        int g = (lane + j) & 63;
        float4 gb = sg[g];
        float sgA = sga[g];
        unsigned long long glo = (unsigned long long)(unsigned)(63 - g);
        unsigned long long pbest = 0ull;
#pragma unroll
        for (int k = 0; k < APT; ++k) {
            float ix0 = fmaxf(ab[k].x, gb.x), iy0 = fmaxf(ab[k].y, gb.y);
            float ix1 = fminf(ab[k].z, gb.z), iy1 = fminf(ab[k].w, gb.w);
            float iw = fmaxf(ix1 - ix0, 0.0f), ih = fmaxf(iy1 - iy0, 0.0f);
            float inter = iw * ih;
            float denom = (sa[k] + sgA) - inter;
            float v = inter * __builtin_amdgcn_rcpf(denom);
            unsigned long long hib = ((unsigned long long)__float_as_uint(v)) << 32;
            unsigned long long kg = hib | glo;
            if (kg > abest[k]) abest[k] = kg;           // tie -> min g
            unsigned long long ka = hib | (unsigned long long)naidx[k];
            if (ka > pbest) pbest = ka;                 // tie -> min anchor idx
        }
        int src = (lane - j) & 63;
        unsigned long long pulled = __shfl(pbest, src, 64);
        if (pulled > gacc) gacc = pulled;
    }

#pragma unroll
    for (int k = 0; k < APT; ++k) {
        float biou = __uint_as_float((unsigned)(abest[k] >> 32));
        unsigned gsel = 63u - (unsigned)(abest[k] & 63ull);
        unsigned char byte = (unsigned char)(((biou > 0.5f) ? 0x80u : 0u) | gsel);
        abyte[(size_t)b * AN + blockbase + k * TPB + tid] = byte;
    }

    skey[wave][lane] = gacc;
    __syncthreads();
    if (tid < GN) {
        unsigned long long kk = skey[0][tid];
#pragma unroll
        for (int w = 1; w < 4; ++w) if (skey[w][tid] > kk) kk = skey[w][tid];
        atomicMax(&gkey[b * GN + tid], kk);
    }
}

// ===================== k_prep =====================
// grid (8, 32), 1024 thr. Each block owns 4096 anchors of one image.
// pos mask, num_pos/loc/posBCE partials, round-1 (top-12-bit) histogram of
// neg-loss -> merged into global per-image hist1.  No vals array.
__global__ __launch_bounds__(1024) void k_prep(const float* __restrict__ bbox,
                                               const float* __restrict__ conf,
                                               const float* __restrict__ gt,
                                               const unsigned long long* __restrict__ gkey,
                                               const unsigned char* __restrict__ abyte,
                                               unsigned* __restrict__ hist1,
                                               int* __restrict__ num_pos,
                                               float* __restrict__ loc_sum,
                                               float* __restrict__ posconf) {
    __shared__ unsigned hist[4096];      // 16 KB
    __shared__ unsigned bitmap[128];     // forced anchors within this 4096 range
    __shared__ float4 sgcs[GN];
    __shared__ float redL[16], redP[16];
    __shared__ int   redN[16];

    int blk = blockIdx.x, b = blockIdx.y, tid = threadIdx.x;
    int abase = blk * 4096;

    for (int i = tid; i < 4096; i += 1024) hist[i] = 0;
    if (tid < 128) bitmap[tid] = 0;
    if (tid < GN) {
        float4 g = ((const float4*)gt)[b * GN + tid];
        sgcs[tid] = make_float4((g.x + g.z) * 0.5f, (g.y + g.w) * 0.5f,
                                g.z - g.x, g.w - g.y);
    }
    __syncthreads();
    if (tid < GN) {
        unsigned long long kk = gkey[b * GN + tid];
        unsigned idx = ~(unsigned)(kk & 0xFFFFFFFFull);
        if ((int)(idx >> 12) == blk)
            atomicOr(&bitmap[(idx & 4095u) >> 5], 1u << (idx & 31u));
    }
    __syncthreads();

    int li = tid * 4;                       // 4 consecutive anchors
    size_t ia = (size_t)b * AN + abase + li;
    float4 c4 = ((const float4*)conf)[ia >> 2];
    uchar4 by4 = ((const uchar4*)abyte)[ia >> 2];
    float cc[4] = {c4.x, c4.y, c4.z, c4.w};
    unsigned bys[4] = {by4.x, by4.y, by4.z, by4.w};
    unsigned fbits = (bitmap[li >> 5] >> (li & 31)) & 0xFu;

    float locv = 0.0f, pcv = 0.0f;
    int npv = 0;
#pragma unroll
    for (int e = 0; e < 4; ++e) {
        float p = cc[e];
        bool pos = (bys[e] & 0x80u) || ((fbits >> e) & 1u);
        float v;
        if (pos) {
            float4 bb = ((const float4*)bbox)[ia + e];
            float4 m = sgcs[bys[e] & 63u];
            float d0 = (bb.x + bb.z) * 0.5f - m.x;
            float d1 = (bb.y + bb.w) * 0.5f - m.y;
            float d2 = (bb.z - bb.x) - m.z;
            float d3 = (bb.w - bb.y) - m.w;
            float ad = fabsf(d0); float s = (ad < 1.0f) ? 0.5f * d0 * d0 : ad - 0.5f;
            ad = fabsf(d1); s += (ad < 1.0f) ? 0.5f * d1 * d1 : ad - 0.5f;
            ad = fabsf(d2); s += (ad < 1.0f) ? 0.5f * d2 * d2 : ad - 0.5f;
            ad = fabsf(d3); s += (ad < 1.0f) ? 0.5f * d3 * d3 : ad - 0.5f;
            locv += s;
            pcv += -fmaxf(logf(p), -100.0f);
            v = 0.0f;
            npv += 1;
        } else {
            v = -fmaxf(log1pf(-p), -100.0f);   // neg_loss > 0
        }
        atomicAdd(&hist[__float_as_uint(v) >> 20], 1u);
    }

    for (int off = 32; off; off >>= 1) {
        locv += __shfl_xor(locv, off);
        pcv  += __shfl_xor(pcv, off);
        npv  += __shfl_xor(npv, off);
    }
    int wave = tid >> 6, lane = tid & 63;
    if (lane == 0) { redL[wave] = locv; redP[wave] = pcv; redN[wave] = npv; }
    __syncthreads();
    if (tid == 0) {
        float L = 0.0f, P = 0.0f; int N = 0;
        for (int w = 0; w < 16; ++w) { L += redL[w]; P += redP[w]; N += redN[w]; }
        if (N) atomicAdd(&num_pos[b], N);
        atomicAdd(&loc_sum[b], L);
        atomicAdd(&posconf[b], P);
    }
    __syncthreads();
    for (int i = tid; i < 4096; i += 1024) {
        unsigned c = hist[i];
        if (c) atomicAdd(&hist1[b * 4096 + i], c);
    }
}

// ===================== k_neg =====================
// One block per image. Load per-image 4096-bin hist, wave-parallel 2-level
// select of round-1 bin, ONE streaming pass over conf (recompute neg-loss,
// sum strictly-above, compact boundary-bin survivors to LDS), two tiny LDS
// radix rounds resolve low 20 bits, write negconf[b].  All compaction in LDS
// -- no contended global atomics.
__global__ __launch_bounds__(1024) void k_neg(const float* __restrict__ conf,
                                              const unsigned char* __restrict__ abyte,
                                              const unsigned long long* __restrict__ gkey,
                                              const unsigned* __restrict__ hist1,
                                              const int* __restrict__ num_pos,
                                              float* __restrict__ negconf) {
    __shared__ unsigned hist[4096];     // 16 KB
    __shared__ float sv[CAP];           // 32 KB
    __shared__ unsigned bitmap[1024];   // 4 KB
    __shared__ float redL[16];
    __shared__ unsigned s_cnt, s_sel, s_krem;

    int b = blockIdx.x, tid = threadIdx.x;
    int lane = tid & 63, wave = tid >> 6;

    for (int i = tid; i < 4096; i += 1024) hist[i] = hist1[b * 4096 + i];
    bitmap[tid] = 0;
    if (tid == 0) s_cnt = 0;
    __syncthreads();
    if (tid < GN) {
        unsigned long long kk = gkey[b * GN + tid];
        unsigned idx = ~(unsigned)(kk & 0xFFFFFFFFull);
        atomicOr(&bitmap[idx >> 5], 1u << (idx & 31));
    }

    int np = num_pos[b];
    unsigned k = (unsigned)min(3 * np, AN - np);
    if (k == 0) { if (tid == 0) negconf[b] = 0.0f; return; }
    __syncthreads();

    // ---- select round 1 over hist[4096] (descending) : two-level wave scan
    if (tid < 64) {
        unsigned c = 0;
        int base = tid * 64;
#pragma unroll
        for (int i = 0; i < 64; ++i) c += hist[base + ((tid + i) & 63)];  // rotated: 2-way banks
        unsigned S = c;
#pragma unroll
        for (int d = 1; d < 64; d <<= 1) { unsigned t = __shfl_down(S, d); if (tid + d < 64) S += t; }
        unsigned E = S - c;                             // suffix-exclusive
        unsigned long long mk = __ballot(E < k && k <= S);
        int bl = __ffsll(mk) - 1;                       // unique boundary lane
        unsigned kin = k - __shfl(E, bl);
        unsigned h = hist[bl * 64 + tid];               // whole wave scans boundary lane's 64 bins
        unsigned S2 = h;
#pragma unroll
        for (int d = 1; d < 64; d <<= 1) { unsigned t = __shfl_down(S2, d); if (tid + d < 64) S2 += t; }
        unsigned E2 = S2 - h;
        unsigned long long mk2 = __ballot(E2 < kin && kin <= S2);
        int bin_l = __ffsll(mk2) - 1;
        unsigned E2b = __shfl(E2, bin_l);
        if (tid == 0) { s_sel = (unsigned)(bl * 64 + bin_l); s_krem = kin - E2b; }
    }
    __syncthreads();
    unsigned sel1 = s_sel, krem1 = s_krem;
    __syncthreads();
    for (int i = tid; i < 4096; i += 1024) hist[i] = 0;
    __syncthreads();

    // ---- ONE streaming pass over conf: strictly-above sum + LDS compaction
    float acc = 0.0f;
    const float4* c4p = (const float4*)(conf + (size_t)b * AN);
    const uchar4* b4p = (const uchar4*)(abyte + (size_t)b * AN);
#pragma unroll
    for (int it = 0; it < 8; ++it) {
        int i4 = tid + it * 1024;
        float4 c4 = c4p[i4];
        uchar4 u4 = b4p[i4];
        int li = i4 * 4;
        unsigned fb = (bitmap[li >> 5] >> (li & 31)) & 0xFu;
        float cc[4] = {c4.x, c4.y, c4.z, c4.w};
        unsigned by[4] = {u4.x, u4.y, u4.z, u4.w};
#pragma unroll
        for (int e = 0; e < 4; ++e) {
            bool pos = (by[e] & 0x80u) || ((fb >> e) & 1u);
            float v = pos ? 0.0f : -fmaxf(log1pf(-cc[e]), -100.0f);
            unsigned bin = __float_as_uint(v) >> 20;
            if (bin > sel1) acc += v;
            else if (bin == sel1) {
                unsigned p = atomicAdd(&s_cnt, 1u);     // LDS atomic, ~1K total
                if (p < CAP) sv[p] = v;
            }
        }
    }
    __syncthreads();
    unsigned n = min(s_cnt, (unsigned)CAP);

    // ---- round A: 12 bits (key>>8)&0xFFF over survivors
    for (unsigned i = tid; i < n; i += 1024)
        atomicAdd(&hist[(__float_as_uint(sv[i]) >> 8) & 0xFFFu], 1u);
    __syncthreads();
    if (tid < 64) {
        unsigned c = 0;
        int base = tid * 64;
#pragma unroll
        for (int i = 0; i < 64; ++i) c += hist[base + ((tid + i) & 63)];
        unsigned S = c;
#pragma unroll
        for (int d = 1; d < 64; d <<= 1) { unsigned t = __shfl_down(S, d); if (tid + d < 64) S += t; }
        unsigned E = S - c;
        unsigned long long mk = __ballot(E < krem1 && krem1 <= S);
        int bl = __ffsll(mk) - 1;
        unsigned kin = krem1 - __shfl(E, bl);
        unsigned h = hist[bl * 64 + tid];
        unsigned S2 = h;
#pragma unroll
        for (int d = 1; d < 64; d <<= 1) { unsigned t = __shfl_down(S2, d); if (tid + d < 64) S2 += t; }
        unsigned E2 = S2 - h;
        unsigned long long mk2 = __ballot(E2 < kin && kin <= S2);
        int bin_l = __ffsll(mk2) - 1;
        unsigned E2b = __shfl(E2, bin_l);
        if (tid == 0) { s_sel = (unsigned)(bl * 64 + bin_l); s_krem = kin - E2b; }
    }
    __syncthreads();
    unsigned selA = s_sel, krem2 = s_krem;
    __syncthreads();
    if (tid < 256) hist[tid] = 0;
    __syncthreads();

    // ---- round B: low 8 bits, masked to selA
    for (unsigned i = tid; i < n; i += 1024) {
        unsigned key = __float_as_uint(sv[i]);
        if (((key >> 8) & 0xFFFu) == selA) atomicAdd(&hist[key & 0xFFu], 1u);
    }
    __syncthreads();
    if (tid < 64) {
        int base = tid * 4;
        unsigned c = 0;
#pragma unroll
        for (int i = 0; i < 4; ++i) c += hist[base + i];
        unsigned S = c;
#pragma unroll
        for (int d = 1; d < 64; d <<= 1) { unsigned t = __shfl_down(S, d); if (tid + d < 64) S += t; }
        unsigned E = S - c;
        unsigned long long mk = __ballot(E < krem2 && krem2 <= S);
        int bl = __ffsll(mk) - 1;
        if (tid == bl) {
            unsigned cum = E;
            for (int bin = base + 3; bin >= base; --bin) {
                unsigned h = hist[bin];
                cum += h;
                if (cum >= krem2) { s_sel = (unsigned)bin; s_krem = krem2 - (cum - h); break; }
            }
        }
    }
    __syncthreads();
    unsigned Tkey = (sel1 << 20) | (selA << 8) | s_sel;
    unsigned kremF = s_krem;
    float T = __uint_as_float(Tkey);   // exact k-th largest value

    float part = acc;
    for (unsigned i = tid; i < n; i += 1024)
        if (__float_as_uint(sv[i]) > Tkey) part += sv[i];
    for (int off = 32; off; off >>= 1) part += __shfl_xor(part, off);
    if (lane == 0) redL[wave] = part;
    __syncthreads();
    if (tid == 0) {
        float t = 0.0f;
        for (int w = 0; w < 16; ++w) t += redL[w];
        negconf[b] = t + (float)kremF * T;
    }
}

// ===================== final reduction =====================
__global__ void k_final(const int* __restrict__ num_pos,
                        const float* __restrict__ loc_sum,
                        const float* __restrict__ posconf,
                        const float* __restrict__ negconf,
                        float* __restrict__ out) {
    int tid = threadIdx.x;
    int np = 0; float lc = 0.0f, pc = 0.0f, nc = 0.0f;
    if (tid < BN) { np = num_pos[tid]; lc = loc_sum[tid]; pc = posconf[tid]; nc = negconf[tid]; }
    for (int off = 32; off; off >>= 1) {
        np += __shfl_xor(np, off); lc += __shfl_xor(lc, off);
        pc += __shfl_xor(pc, off); nc += __shfl_xor(nc, off);
    }
    if (tid == 0) {
        float tp = (float)max(1, np);
        float loc_loss = lc / tp;
        float conf_loss = (pc + nc) / tp;
        out[0] = loc_loss + conf_loss;
        out[1] = conf_loss;
        out[2] = loc_loss;
    }
}

extern "C" void kernel_launch(void* const* d_in, const int* in_sizes, int n_in,
                              void* d_out, int out_size, void* d_ws, size_t ws_size,
                              hipStream_t stream) {
    const float* bbox    = (const float*)d_in[0];   // [B,A,4]
    const float* conf    = (const float*)d_in[1];   // [B,A]
    const float* anchors = (const float*)d_in[2];   // [A,4]
    const float* gt      = (const float*)d_in[3];   // [B,G,4]
    float* out = (float*)d_out;

    // zero scalars + gkey + hist1 (abyte fully overwritten by k_fused)
    hipMemsetAsync(d_ws, 0, WS_MEMSET, stream);

    dim3 g1(AN / ANCH_PER_BLK, BN);   // (32, 32)
    k_fused<<<g1, TPB, 0, stream>>>(anchors, gt, WS_GKEY(d_ws), WS_ABYTE(d_ws));

    dim3 g2(8, BN);
    k_prep<<<g2, 1024, 0, stream>>>(bbox, conf, gt, WS_GKEY(d_ws), WS_ABYTE(d_ws),
                                    WS_HIST1(d_ws),
                                    WS_NUMPOS(d_ws), WS_LOC(d_ws), WS_PCONF(d_ws));

    k_neg<<<BN, 1024, 0, stream>>>(conf, WS_ABYTE(d_ws), WS_GKEY(d_ws), WS_HIST1(d_ws),
                                   WS_NUMPOS(d_ws), WS_NCONF(d_ws));

    k_final<<<1, 64, 0, stream>>>(WS_NUMPOS(d_ws), WS_LOC(d_ws), WS_PCONF(d_ws),
                                  WS_NCONF(d_ws), out);
}

// Round 7
// 97.536 us; speedup vs baseline: 1.6749x; 1.0285x over previous
//
#include <hip/hip_runtime.h>
#include <cmath>

#define BN 32
#define AN 32768
#define GN 64
#define APT 2                      // anchors per thread in k_fused
#define TPB 256                    // threads per block in k_fused
#define ANCH_PER_BLK (APT * TPB)   // 512
#define NBLK 8                     // k_prep blocks per image
#define CAP 8192                   // LDS survivor capacity in k_neg

// ---------------- workspace layout (bytes) ----------------
// 0       : int    num_pos[32]
// 128     : float  loc_sum[32]
// 256     : float  posconf[32]
// 384     : float  negconf[32]
// 1024    : u64    gkey[B*G]            (16 KB)
// 17408   : uint   hist1[B][NBLK][4096] (4 MB, plain stores - no memset)
// 4211712 : u8     abyte[B*A]           (1 MB, fully overwritten)
#define WS_NUMPOS(ws)  ((int*)(ws))
#define WS_LOC(ws)     ((float*)((char*)(ws) + 128))
#define WS_PCONF(ws)   ((float*)((char*)(ws) + 256))
#define WS_NCONF(ws)   ((float*)((char*)(ws) + 384))
#define WS_GKEY(ws)    ((unsigned long long*)((char*)(ws) + 1024))
#define WS_HIST1(ws)   ((unsigned*)((char*)(ws) + 17408))
#define WS_ABYTE(ws)   ((unsigned char*)((char*)(ws) + 4211712))
#define WS_MEMSET      17408       // scalars + gkey only

// ===================== fused IoU pass =====================
// Every (anchor, gt) IoU computed exactly once.
// per-anchor best over g: plain float strict-> compare (rotated order);
// per-gt best over anchors: 2->1 in-thread reduce (exact, min-idx ties) then
// LDS atomicMax on u64 key = (iou_bits<<32) | ~anchor_idx  (no shfl chain),
// block result -> global atomicMax.
__global__ __launch_bounds__(TPB, 8) void k_fused(const float* __restrict__ anchors,
                                                  const float* __restrict__ gt,
                                                  unsigned long long* __restrict__ gkey,
                                                  unsigned char* __restrict__ abyte) {
    __shared__ float sgt[5][GN];               // x0,y0,x1,y1,area (SoA)
    __shared__ unsigned long long skey2[GN];

    int b = blockIdx.y;
    int tid = threadIdx.x;
    int lane = tid & 63;
    int blockbase = blockIdx.x * ANCH_PER_BLK;

    if (tid < GN) {
        float4 g = ((const float4*)gt)[b * GN + tid];
        sgt[0][tid] = g.x; sgt[1][tid] = g.y;
        sgt[2][tid] = g.z; sgt[3][tid] = g.w;
        sgt[4][tid] = (g.z - g.x) * (g.w - g.y);
        skey2[tid] = 0ull;
    }
    __syncthreads();

    unsigned a0 = (unsigned)(blockbase + tid);
    unsigned a1 = a0 + TPB;
    float4 ab0 = ((const float4*)anchors)[a0];
    float4 ab1 = ((const float4*)anchors)[a1];
    float sa0 = (ab0.z - ab0.x) * (ab0.w - ab0.y) + 1e-6f;
    float sa1 = (ab1.z - ab1.x) * (ab1.w - ab1.y) + 1e-6f;

    float bv0 = -1.0f, bv1 = -1.0f;
    int bg0 = 0, bg1 = 0;

#pragma unroll 4
    for (int j = 0; j < GN; ++j) {
        int g = (lane + j) & 63;
        float gx0 = sgt[0][g], gy0 = sgt[1][g];
        float gx1 = sgt[2][g], gy1 = sgt[3][g];
        float gA  = sgt[4][g];

        float ix0 = fmaxf(ab0.x, gx0), iy0 = fmaxf(ab0.y, gy0);
        float ix1 = fminf(ab0.z, gx1), iy1 = fminf(ab0.w, gy1);
        float iw = fmaxf(ix1 - ix0, 0.0f), ih = fmaxf(iy1 - iy0, 0.0f);
        float inter0 = iw * ih;
        float v0 = inter0 * __builtin_amdgcn_rcpf((sa0 + gA) - inter0);

        ix0 = fmaxf(ab1.x, gx0); iy0 = fmaxf(ab1.y, gy0);
        ix1 = fminf(ab1.z, gx1); iy1 = fminf(ab1.w, gy1);
        iw = fmaxf(ix1 - ix0, 0.0f); ih = fmaxf(iy1 - iy0, 0.0f);
        float inter1 = iw * ih;
        float v1 = inter1 * __builtin_amdgcn_rcpf((sa1 + gA) - inter1);

        if (v0 > bv0) { bv0 = v0; bg0 = g; }
        if (v1 > bv1) { bv1 = v1; bg1 = g; }

        // per-gt: 2->1 (a0 < a1, strict > keeps min idx on exact ties)
        float vm = v0; unsigned am = a0;
        if (v1 > vm) { vm = v1; am = a1; }
        unsigned long long key = ((unsigned long long)__float_as_uint(vm) << 32)
                               | (unsigned long long)(~am);
        atomicMax(&skey2[g], key);     // ds_max_u64, no return -> no dep chain
    }
    __syncthreads();

    size_t base = (size_t)b * AN;
    abyte[base + a0] = (unsigned char)(((bv0 > 0.5f) ? 0x80u : 0u) | (unsigned)bg0);
    abyte[base + a1] = (unsigned char)(((bv1 > 0.5f) ? 0x80u : 0u) | (unsigned)bg1);

    if (tid < GN) {
        unsigned long long kk = skey2[tid];
        atomicMax(&gkey[b * GN + tid], kk);
    }
}

// ===================== k_prep =====================
// grid (NBLK, 32), 1024 thr. Each block owns 4096 anchors of one image.
// pos mask, num_pos/loc/posBCE partials, round-1 (top-12-bit) histogram of
// neg-loss -> PLAIN stores into its own hist1 slice (no atomics, no memset).
__global__ __launch_bounds__(1024) void k_prep(const float* __restrict__ bbox,
                                               const float* __restrict__ conf,
                                               const float* __restrict__ gt,
                                               const unsigned long long* __restrict__ gkey,
                                               const unsigned char* __restrict__ abyte,
                                               unsigned* __restrict__ hist1,
                                               int* __restrict__ num_pos,
                                               float* __restrict__ loc_sum,
                                               float* __restrict__ posconf) {
    __shared__ unsigned hist[4096];      // 16 KB
    __shared__ unsigned bitmap[128];     // forced anchors within this 4096 range
    __shared__ float4 sgcs[GN];
    __shared__ float redL[16], redP[16];
    __shared__ int   redN[16];

    int blk = blockIdx.x, b = blockIdx.y, tid = threadIdx.x;
    int abase = blk * 4096;

    for (int i = tid; i < 4096; i += 1024) hist[i] = 0;
    if (tid < 128) bitmap[tid] = 0;
    if (tid < GN) {
        float4 g = ((const float4*)gt)[b * GN + tid];
        sgcs[tid] = make_float4((g.x + g.z) * 0.5f, (g.y + g.w) * 0.5f,
                                g.z - g.x, g.w - g.y);
    }
    __syncthreads();
    if (tid < GN) {
        unsigned long long kk = gkey[b * GN + tid];
        unsigned idx = ~(unsigned)(kk & 0xFFFFFFFFull);
        if ((int)(idx >> 12) == blk)
            atomicOr(&bitmap[(idx & 4095u) >> 5], 1u << (idx & 31u));
    }
    __syncthreads();

    int li = tid * 4;                       // 4 consecutive anchors
    size_t ia = (size_t)b * AN + abase + li;
    float4 c4 = ((const float4*)conf)[ia >> 2];
    uchar4 by4 = ((const uchar4*)abyte)[ia >> 2];
    float cc[4] = {c4.x, c4.y, c4.z, c4.w};
    unsigned bys[4] = {by4.x, by4.y, by4.z, by4.w};
    unsigned fbits = (bitmap[li >> 5] >> (li & 31)) & 0xFu;

    float locv = 0.0f, pcv = 0.0f;
    int npv = 0;
#pragma unroll
    for (int e = 0; e < 4; ++e) {
        float p = cc[e];
        bool pos = (bys[e] & 0x80u) || ((fbits >> e) & 1u);
        float v;
        if (pos) {
            float4 bb = ((const float4*)bbox)[ia + e];
            float4 m = sgcs[bys[e] & 63u];
            float d0 = (bb.x + bb.z) * 0.5f - m.x;
            float d1 = (bb.y + bb.w) * 0.5f - m.y;
            float d2 = (bb.z - bb.x) - m.z;
            float d3 = (bb.w - bb.y) - m.w;
            float ad = fabsf(d0); float s = (ad < 1.0f) ? 0.5f * d0 * d0 : ad - 0.5f;
            ad = fabsf(d1); s += (ad < 1.0f) ? 0.5f * d1 * d1 : ad - 0.5f;
            ad = fabsf(d2); s += (ad < 1.0f) ? 0.5f * d2 * d2 : ad - 0.5f;
            ad = fabsf(d3); s += (ad < 1.0f) ? 0.5f * d3 * d3 : ad - 0.5f;
            locv += s;
            pcv += -fmaxf(logf(p), -100.0f);
            v = 0.0f;
            npv += 1;
        } else {
            v = -fmaxf(log1pf(-p), -100.0f);   // neg_loss > 0
        }
        atomicAdd(&hist[__float_as_uint(v) >> 20], 1u);
    }

    for (int off = 32; off; off >>= 1) {
        locv += __shfl_xor(locv, off);
        pcv  += __shfl_xor(pcv, off);
        npv  += __shfl_xor(npv, off);
    }
    int wave = tid >> 6, lane = tid & 63;
    if (lane == 0) { redL[wave] = locv; redP[wave] = pcv; redN[wave] = npv; }
    __syncthreads();
    if (tid == 0) {
        float L = 0.0f, P = 0.0f; int N = 0;
        for (int w = 0; w < 16; ++w) { L += redL[w]; P += redP[w]; N += redN[w]; }
        if (N) atomicAdd(&num_pos[b], N);
        atomicAdd(&loc_sum[b], L);
        atomicAdd(&posconf[b], P);
    }
    __syncthreads();
    unsigned* hslice = hist1 + (size_t)(b * NBLK + blk) * 4096;
    for (int i = tid; i < 4096; i += 1024) hslice[i] = hist[i];
}

// ===================== k_neg =====================
// One block per image. Sum the NBLK sub-histograms, wave-parallel 2-level
// select of round-1 bin, ONE streaming pass over conf (recompute neg-loss,
// sum strictly-above, compact boundary-bin survivors to LDS), two tiny LDS
// radix rounds resolve low 20 bits, write negconf[b].
__global__ __launch_bounds__(1024) void k_neg(const float* __restrict__ conf,
                                              const unsigned char* __restrict__ abyte,
                                              const unsigned long long* __restrict__ gkey,
                                              const unsigned* __restrict__ hist1,
                                              const int* __restrict__ num_pos,
                                              float* __restrict__ negconf) {
    __shared__ unsigned hist[4096];     // 16 KB
    __shared__ float sv[CAP];           // 32 KB
    __shared__ unsigned bitmap[1024];   // 4 KB
    __shared__ float redL[16];
    __shared__ unsigned s_cnt, s_sel, s_krem;

    int b = blockIdx.x, tid = threadIdx.x;
    int lane = tid & 63, wave = tid >> 6;

    for (int i = tid; i < 4096; i += 1024) {
        unsigned s = 0;
#pragma unroll
        for (int t = 0; t < NBLK; ++t)
            s += hist1[(size_t)(b * NBLK + t) * 4096 + i];
        hist[i] = s;
    }
    bitmap[tid] = 0;
    if (tid == 0) s_cnt = 0;
    __syncthreads();
    if (tid < GN) {
        unsigned long long kk = gkey[b * GN + tid];
        unsigned idx = ~(unsigned)(kk & 0xFFFFFFFFull);
        atomicOr(&bitmap[idx >> 5], 1u << (idx & 31));
    }

    int np = num_pos[b];
    unsigned k = (unsigned)min(3 * np, AN - np);
    if (k == 0) { if (tid == 0) negconf[b] = 0.0f; return; }
    __syncthreads();

    // ---- select round 1 over hist[4096] (descending): two-level wave scan
    if (tid < 64) {
        unsigned c = 0;
        int base = tid * 64;
#pragma unroll
        for (int i = 0; i < 64; ++i) c += hist[base + ((tid + i) & 63)];  // rotated: 2-way banks
        unsigned S = c;
#pragma unroll
        for (int d = 1; d < 64; d <<= 1) { unsigned t = __shfl_down(S, d); if (tid + d < 64) S += t; }
        unsigned E = S - c;                             // suffix-exclusive
        unsigned long long mk = __ballot(E < k && k <= S);
        int bl = __ffsll(mk) - 1;                       // unique boundary lane
        unsigned kin = k - __shfl(E, bl);
        unsigned h = hist[bl * 64 + tid];               // wave scans boundary lane's 64 bins
        unsigned S2 = h;
#pragma unroll
        for (int d = 1; d < 64; d <<= 1) { unsigned t = __shfl_down(S2, d); if (tid + d < 64) S2 += t; }
        unsigned E2 = S2 - h;
        unsigned long long mk2 = __ballot(E2 < kin && kin <= S2);
        int bin_l = __ffsll(mk2) - 1;
        unsigned E2b = __shfl(E2, bin_l);
        if (tid == 0) { s_sel = (unsigned)(bl * 64 + bin_l); s_krem = kin - E2b; }
    }
    __syncthreads();
    unsigned sel1 = s_sel, krem1 = s_krem;
    __syncthreads();
    for (int i = tid; i < 4096; i += 1024) hist[i] = 0;
    __syncthreads();

    // ---- ONE streaming pass over conf: strictly-above sum + LDS compaction
    float acc = 0.0f;
    const float4* c4p = (const float4*)(conf + (size_t)b * AN);
    const uchar4* b4p = (const uchar4*)(abyte + (size_t)b * AN);
#pragma unroll
    for (int it = 0; it < 8; ++it) {
        int i4 = tid + it * 1024;
        float4 c4 = c4p[i4];
        uchar4 u4 = b4p[i4];
        int li = i4 * 4;
        unsigned fb = (bitmap[li >> 5] >> (li & 31)) & 0xFu;
        float cc[4] = {c4.x, c4.y, c4.z, c4.w};
        unsigned by[4] = {u4.x, u4.y, u4.z, u4.w};
#pragma unroll
        for (int e = 0; e < 4; ++e) {
            bool pos = (by[e] & 0x80u) || ((fb >> e) & 1u);
            float v = pos ? 0.0f : -fmaxf(log1pf(-cc[e]), -100.0f);
            unsigned bin = __float_as_uint(v) >> 20;
            if (bin > sel1) acc += v;
            else if (bin == sel1) {
                unsigned p = atomicAdd(&s_cnt, 1u);     // LDS atomic, ~1K total
                if (p < CAP) sv[p] = v;
            }
        }
    }
    __syncthreads();
    unsigned n = min(s_cnt, (unsigned)CAP);

    // ---- round A: 12 bits (key>>8)&0xFFF over survivors
    for (unsigned i = tid; i < n; i += 1024)
        atomicAdd(&hist[(__float_as_uint(sv[i]) >> 8) & 0xFFFu], 1u);
    __syncthreads();
    if (tid < 64) {
        unsigned c = 0;
        int base = tid * 64;
#pragma unroll
        for (int i = 0; i < 64; ++i) c += hist[base + ((tid + i) & 63)];
        unsigned S = c;
#pragma unroll
        for (int d = 1; d < 64; d <<= 1) { unsigned t = __shfl_down(S, d); if (tid + d < 64) S += t; }
        unsigned E = S - c;
        unsigned long long mk = __ballot(E < krem1 && krem1 <= S);
        int bl = __ffsll(mk) - 1;
        unsigned kin = krem1 - __shfl(E, bl);
        unsigned h = hist[bl * 64 + tid];
        unsigned S2 = h;
#pragma unroll
        for (int d = 1; d < 64; d <<= 1) { unsigned t = __shfl_down(S2, d); if (tid + d < 64) S2 += t; }
        unsigned E2 = S2 - h;
        unsigned long long mk2 = __ballot(E2 < kin && kin <= S2);
        int bin_l = __ffsll(mk2) - 1;
        unsigned E2b = __shfl(E2, bin_l);
        if (tid == 0) { s_sel = (unsigned)(bl * 64 + bin_l); s_krem = kin - E2b; }
    }
    __syncthreads();
    unsigned selA = s_sel, krem2 = s_krem;
    __syncthreads();
    if (tid < 256) hist[tid] = 0;
    __syncthreads();

    // ---- round B: low 8 bits, masked to selA
    for (unsigned i = tid; i < n; i += 1024) {
        unsigned key = __float_as_uint(sv[i]);
        if (((key >> 8) & 0xFFFu) == selA) atomicAdd(&hist[key & 0xFFu], 1u);
    }
    __syncthreads();
    if (tid < 64) {
        int base = tid * 4;
        unsigned c = 0;
#pragma unroll
        for (int i = 0; i < 4; ++i) c += hist[base + i];
        unsigned S = c;
#pragma unroll
        for (int d = 1; d < 64; d <<= 1) { unsigned t = __shfl_down(S, d); if (tid + d < 64) S += t; }
        unsigned E = S - c;
        unsigned long long mk = __ballot(E < krem2 && krem2 <= S);
        int bl = __ffsll(mk) - 1;
        if (tid == bl) {
            unsigned cum = E;
            for (int bin = base + 3; bin >= base; --bin) {
                unsigned h = hist[bin];
                cum += h;
                if (cum >= krem2) { s_sel = (unsigned)bin; s_krem = krem2 - (cum - h); break; }
            }
        }
    }
    __syncthreads();
    unsigned Tkey = (sel1 << 20) | (selA << 8) | s_sel;
    unsigned kremF = s_krem;
    float T = __uint_as_float(Tkey);   // exact k-th largest value

    float part = acc;
    for (unsigned i = tid; i < n; i += 1024)
        if (__float_as_uint(sv[i]) > Tkey) part += sv[i];
    for (int off = 32; off; off >>= 1) part += __shfl_xor(part, off);
    if (lane == 0) redL[wave] = part;
    __syncthreads();
    if (tid == 0) {
        float t = 0.0f;
        for (int w = 0; w < 16; ++w) t += redL[w];
        negconf[b] = t + (float)kremF * T;
    }
}

// ===================== final reduction =====================
__global__ void k_final(const int* __restrict__ num_pos,
                        const float* __restrict__ loc_sum,
                        const float* __restrict__ posconf,
                        const float* __restrict__ negconf,
                        float* __restrict__ out) {
    int tid = threadIdx.x;
    int np = 0; float lc = 0.0f, pc = 0.0f, nc = 0.0f;
    if (tid < BN) { np = num_pos[tid]; lc = loc_sum[tid]; pc = posconf[tid]; nc = negconf[tid]; }
    for (int off = 32; off; off >>= 1) {
        np += __shfl_xor(np, off); lc += __shfl_xor(lc, off);
        pc += __shfl_xor(pc, off); nc += __shfl_xor(nc, off);
    }
    if (tid == 0) {
        float tp = (float)max(1, np);
        float loc_loss = lc / tp;
        float conf_loss = (pc + nc) / tp;
        out[0] = loc_loss + conf_loss;
        out[1] = conf_loss;
        out[2] = loc_loss;
    }
}

extern "C" void kernel_launch(void* const* d_in, const int* in_sizes, int n_in,
                              void* d_out, int out_size, void* d_ws, size_t ws_size,
                              hipStream_t stream) {
    const float* bbox    = (const float*)d_in[0];   // [B,A,4]
    const float* conf    = (const float*)d_in[1];   // [B,A]
    const float* anchors = (const float*)d_in[2];   // [A,4]
    const float* gt      = (const float*)d_in[3];   // [B,G,4]
    float* out = (float*)d_out;

    // zero scalars + gkey only (hist1 plain-stored, abyte fully overwritten)
    hipMemsetAsync(d_ws, 0, WS_MEMSET, stream);

    dim3 g1(AN / ANCH_PER_BLK, BN);   // (64, 32) = 2048 blocks -> 32 waves/CU
    k_fused<<<g1, TPB, 0, stream>>>(anchors, gt, WS_GKEY(d_ws), WS_ABYTE(d_ws));

    dim3 g2(NBLK, BN);
    k_prep<<<g2, 1024, 0, stream>>>(bbox, conf, gt, WS_GKEY(d_ws), WS_ABYTE(d_ws),
                                    WS_HIST1(d_ws),
                                    WS_NUMPOS(d_ws), WS_LOC(d_ws), WS_PCONF(d_ws));

    k_neg<<<BN, 1024, 0, stream>>>(conf, WS_ABYTE(d_ws), WS_GKEY(d_ws), WS_HIST1(d_ws),
                                   WS_NUMPOS(d_ws), WS_NCONF(d_ws));

    k_final<<<1, 64, 0, stream>>>(WS_NUMPOS(d_ws), WS_LOC(d_ws), WS_PCONF(d_ws),
                                  WS_NCONF(d_ws), out);
}